// Round 6
// baseline (111.421 us; speedup 1.0000x reference)
//
#include <hip/hip_runtime.h>
#include <hip/hip_bf16.h>
#include <stdint.h>

#define K_DIM 1024
#define N_DIM 1024
#define NKT 16   // K / 64

typedef __attribute__((ext_vector_type(8))) short  short8;
typedef __attribute__((ext_vector_type(4))) float  f32x4;
typedef __attribute__((ext_vector_type(4))) unsigned int u32x4;

__device__ __forceinline__ ushort f2bf(float f) {
  union { float f; uint32_t u; } v; v.f = f;
  uint32_t r = v.u + 0x7FFFu + ((v.u >> 16) & 1u);
  return (ushort)(r >> 16);
}
__device__ __forceinline__ uint32_t pack_bf2(float a, float b) {
  __hip_bfloat162 h = __float22bfloat162_rn(make_float2(a, b));
  union { __hip_bfloat162 h; uint32_t u; } c; c.h = h;
  return c.u;
}

// ---------------- kernel 1: materialize Toeplitz matrix as bf16 -------------
__global__ __launch_bounds__(256) void build_T_kernel(
    const float* __restrict__ fr, const float* __restrict__ fc,
    ushort* __restrict__ T) {
  int idx = blockIdx.x * 256 + threadIdx.x;
  int o  = idx >> 7;
  int i0 = (idx & 127) << 3;
  short8 v;
#pragma unroll
  for (int j = 0; j < 8; ++j) {
    int d = o - (i0 + j);
    float f = (d >= 0) ? fc[d] : fr[-d];
    v[j] = (short)f2bf(f);
  }
  *reinterpret_cast<short8*>(T + (size_t)idx * 8) = v;
}

// ---- kernel 2: 128x256 tile, 16 waves of 32x64, 4 waves/SIMD ---------------
__global__ __launch_bounds__(1024, 4) void toeplitz_gemm(
    const float* __restrict__ X, const ushort* __restrict__ T,
    const float* __restrict__ bias, float* __restrict__ Out) {
  // LDS: A dbuf 2x16KB @0, B dbuf 2x32KB @32768  => 96 KiB
  __shared__ alignas(16) char smem[98304];

  const int tid  = threadIdx.x;
  const int lane = tid & 63;
  const int wv   = tid >> 6;           // 0..15
  const int wm   = wv >> 2;            // 0..3 (m, x32 rows)
  const int wn   = wv & 3;             // 0..3 (n, x64 cols)
  const int cc   = lane & 15, kg = lane >> 4;

  // XCD swizzle: 1024 blocks = 8 xcd * 128; 4 consecutive swz share x-panel.
  const int swz = (blockIdx.x & 7) * 128 + (blockIdx.x >> 3);
  const int m0 = (swz >> 2) * 128;
  const int n0 = (swz & 3) * 256;

  // ---- A staging (reg-stage fp32 -> bf16, swizzled ds_write_b128) ----
  const int arow = tid >> 3, aslot = tid & 7;
  const float* xptr = X + (size_t)(m0 + arow) * K_DIM + aslot * 8;
  const int aW = arow * 128 + ((aslot * 16) ^ ((arow & 7) << 4)); // + sel*16384

  // ---- B staging (global_load_lds, pre-swizzled source) ----
  const int brow = tid >> 3;           // + g*128
  const ushort* tptr = T + (size_t)(n0 + brow) * K_DIM
                         + ((((tid & 7) * 16) ^ ((brow & 7) << 4)) >> 1);
  const int bLds = 32768 + tid * 16;   // + sel*32768 + g*16384

  const int fXor = (cc & 7) << 4;

  f32x4  areg[2];
  short8 afr[2][2];     // mf, kk
  short8 bfr[2][2];     // nf-in-group, kk
  f32x4  acc[2][4] = {};

#define SB0() __builtin_amdgcn_sched_barrier(0)

#define ISSUE_A(t)                                                          \
  { _Pragma("unroll")                                                       \
    for (int j = 0; j < 2; ++j)                                             \
      areg[j] = *reinterpret_cast<const f32x4*>(xptr + (t) * 64 + j * 4); }

#define ISSUE_B(t, sel)                                                     \
  { _Pragma("unroll")                                                       \
    for (int g = 0; g < 2; ++g) {                                           \
      const ushort* src = tptr + (size_t)g * 128 * K_DIM + (t) * 64;        \
      char* dst = smem + bLds + (sel) * 32768 + g * 16384;                  \
      __builtin_amdgcn_global_load_lds(                                     \
          (const __attribute__((address_space(1))) void*)src,               \
          (__attribute__((address_space(3))) void*)dst, 16, 0, 0);          \
    } }

#define CVT_WRITE_A(sel)                                                    \
  { u32x4 p;                                                                \
    p.x = pack_bf2(areg[0].x, areg[0].y);                                   \
    p.y = pack_bf2(areg[0].z, areg[0].w);                                   \
    p.z = pack_bf2(areg[1].x, areg[1].y);                                   \
    p.w = pack_bf2(areg[1].z, areg[1].w);                                   \
    *reinterpret_cast<u32x4*>(smem + (sel) * 16384 + aW) = p; }

#define READ_AFR(sel)                                                       \
  { _Pragma("unroll")                                                       \
    for (int mf = 0; mf < 2; ++mf)                                          \
      _Pragma("unroll")                                                     \
      for (int kk = 0; kk < 2; ++kk)                                        \
        afr[mf][kk] = *reinterpret_cast<const short8*>(                     \
            smem + (sel) * 16384 +                                          \
            (wm * 32 + mf * 16 + cc) * 128 +                                \
            ((kk * 64 + kg * 16) ^ fXor)); }

#define READ_BFR(sel, nfg)                                                  \
  { _Pragma("unroll")                                                       \
    for (int nf = 0; nf < 2; ++nf)                                          \
      _Pragma("unroll")                                                     \
      for (int kk = 0; kk < 2; ++kk)                                        \
        bfr[nf][kk] = *reinterpret_cast<const short8*>(                     \
            smem + 32768 + (sel) * 32768 +                                  \
            (wn * 64 + ((nfg) * 2 + nf) * 16 + cc) * 128 +                  \
            ((kk * 64 + kg * 16) ^ fXor)); }

#define MFMA_G(nfg)                                                         \
  { __builtin_amdgcn_s_setprio(1);                                         \
    _Pragma("unroll")                                                       \
    for (int mf = 0; mf < 2; ++mf)                                          \
      _Pragma("unroll")                                                     \
      for (int nf = 0; nf < 2; ++nf)                                        \
        _Pragma("unroll")                                                   \
        for (int kk = 0; kk < 2; ++kk)                                      \
          acc[mf][(nfg) * 2 + nf] = __builtin_amdgcn_mfma_f32_16x16x32_bf16( \
              afr[mf][kk], bfr[nf][kk], acc[mf][(nfg) * 2 + nf], 0, 0, 0);   \
    __builtin_amdgcn_s_setprio(0); }

  // ---- prologue: stage K-tile 0 into buf0 ----
  ISSUE_A(0); SB0();
  ISSUE_B(0, 0); SB0();
  CVT_WRITE_A(0);                 // compiler waits A(0) via counted vmcnt
  asm volatile("s_waitcnt vmcnt(0) lgkmcnt(0)" ::: "memory");
  __builtin_amdgcn_s_barrier();

#pragma unroll 1
  for (int t = 0; t < NKT; ++t) {
    const int c = t & 1, n = c ^ 1;
    if (t + 1 < NKT) { ISSUE_A(t + 1); SB0(); ISSUE_B(t + 1, n); SB0(); }
    READ_AFR(c);
    READ_BFR(c, 0);
    MFMA_G(0);
    READ_BFR(c, 1);
    MFMA_G(1);
    if (t + 1 < NKT) {
      CVT_WRITE_A(n);             // waits vmcnt(2): A older than 2 B-DMAs
      asm volatile("s_waitcnt vmcnt(0) lgkmcnt(0)" ::: "memory"); // B DMA + A write
      __builtin_amdgcn_s_barrier();
    }
  }

  // ---- epilogue: bias + fp32 store ----
#pragma unroll
  for (int nf = 0; nf < 4; ++nf) {
    const int col = n0 + wn * 64 + nf * 16 + cc;
    const float bv = bias[col];
#pragma unroll
    for (int mf = 0; mf < 2; ++mf) {
      const int row0 = m0 + wm * 32 + mf * 16 + kg * 4;
      float* op = Out + (size_t)row0 * N_DIM + col;
#pragma unroll
      for (int j = 0; j < 4; ++j)
        op[(size_t)j * N_DIM] = acc[mf][nf][j] + bv;
    }
  }
#undef ISSUE_A
#undef ISSUE_B
#undef CVT_WRITE_A
#undef READ_AFR
#undef READ_BFR
#undef MFMA_G
#undef SB0
}

// ---------------- fallback (ws too small): naive fp32 ----------------------
__global__ __launch_bounds__(256) void toeplitz_naive(
    const float* __restrict__ x, const float* __restrict__ fr,
    const float* __restrict__ fc, const float* __restrict__ bias,
    float* __restrict__ out) {
  __shared__ float sx[1024], sfr[1024], sfc[1024];
  const int m = blockIdx.x;
  for (int i = threadIdx.x; i < 1024; i += 256) {
    sx[i]  = x[(size_t)m * 1024 + i];
    sfr[i] = fr[i];
    sfc[i] = fc[i];
  }
  __syncthreads();
  for (int q = 0; q < 4; ++q) {
    const int o = threadIdx.x + q * 256;
    float acc = bias[o];
    for (int i = 0; i <= o; ++i)       acc += sx[i] * sfc[o - i];
    for (int i = o + 1; i < 1024; ++i) acc += sx[i] * sfr[i - o];
    out[(size_t)m * 1024 + o] = acc;
  }
}

extern "C" void kernel_launch(void* const* d_in, const int* in_sizes, int n_in,
                              void* d_out, int out_size, void* d_ws, size_t ws_size,
                              hipStream_t stream) {
  const float* x    = (const float*)d_in[0];
  const float* fr   = (const float*)d_in[1];
  const float* fc   = (const float*)d_in[2];
  const float* bias = (const float*)d_in[3];
  float* out = (float*)d_out;

  if (ws_size >= (size_t)2 * 1024 * 1024) {
    ushort* T = (ushort*)d_ws;
    build_T_kernel<<<dim3(512), dim3(256), 0, stream>>>(fr, fc, T);
    toeplitz_gemm<<<dim3(1024), dim3(1024), 0, stream>>>(x, T, bias, out);
  } else {
    toeplitz_naive<<<dim3(32768), dim3(256), 0, stream>>>(x, fr, fc, bias, out);
  }
}